// Round 1
// baseline (132.069 us; speedup 1.0000x reference)
//
#include <hip/hip_runtime.h>

// relative_pos_embedding: out[b,h,t,r] = sum_d q[b,h,t,d] * emb[h, idx[r,t], d]
// idx[r,t] = (t - r) mod 1023 (Toeplitz) -> per 128x128 (t,r) tile the needed
// emb rows are a contiguous band of 255 rows (mod 1023), staged once in LDS.

#define BATCH 8
#define HEADS 8
#define TOKENS 512
#define DIMH 64
#define NREL 1023
#define IDXN 1490

#define TT 128          // t-tile
#define TR 128          // r-tile
#define BAND 255        // TT + TR - 1
#define EB_STRIDE 256   // padded band rows
#define NTHREADS 512
#define BG 4            // batches per block (2 batch-groups)

__global__ __launch_bounds__(NTHREADS, 2)
void relpos_kernel(const float* __restrict__ q,
                   const float* __restrict__ emb,
                   const int* __restrict__ indices,
                   float* __restrict__ out)
{
    // transposed LDS tiles: row index contiguous for vector reads in compute
    __shared__ float EBt[DIMH][EB_STRIDE]; // [d][band_row]  64 KB
    __shared__ float QTt[DIMH][TT];        // [d][u]         32 KB

    const int tid = threadIdx.x;
    const int blk = blockIdx.x;          // 256 blocks: tr(4) tt(4) h(8) bg(2)
    const int tr = blk & 3;
    const int tt = (blk >> 2) & 3;
    const int h  = (blk >> 4) & 7;
    const int bg = (blk >> 7) & 1;

    const int t0 = tt * TT;
    const int r0 = tr * TR;

    // minimal band row: j(r,t) = (j_base + (t-t0) + (r0+TR-1-r)) mod NREL
    const int j_base = indices[(size_t)(r0 + TR - 1) * IDXN + t0];

    // ---- stage E band (once per block), row-fast so LDS writes conflict-free
    {
        const float* embh = emb + (size_t)h * NREL * DIMH;
        const int c4 = tid >> 5;         // 16 groups: which float4 chunk of d
        const int rl = tid & 31;         // lane-in-group -> consecutive rows
        for (int row = rl; row < BAND; row += 32) {
            int j = j_base + row;
            if (j >= NREL) j -= NREL;
            const float4 v = *(const float4*)(embh + (size_t)j * DIMH + c4 * 4);
            EBt[c4 * 4 + 0][row] = v.x;
            EBt[c4 * 4 + 1][row] = v.y;
            EBt[c4 * 4 + 2][row] = v.z;
            EBt[c4 * 4 + 3][row] = v.w;
        }
    }

    // compute-thread mapping: v (=r) lane-fast for coalesced output stores
    const int vpos = tid & 15;           // 16 v positions * 8 = 128 r
    const int upos = tid >> 4;           // 32 u positions * 4 = 128 t
    const int v0 = vpos * 8;
    const int u0 = upos * 4;
    const int m = u0 - v0 + (TR - 8);    // band row base; multiple of 4 -> aligned

    const int c4 = tid >> 5;
    const int rl = tid & 31;

    for (int bi = 0; bi < BG; ++bi) {
        const int b = bg * BG + bi;
        __syncthreads();                 // covers E-stage (first) / prev compute

        // ---- stage Q tile for this b: Q[b][h][t0+u][d] -> QTt[d][u]
        const float* qb = q + (((size_t)b * HEADS + h) * TOKENS + t0) * DIMH;
        for (int u = rl; u < TT; u += 32) {
            const float4 v = *(const float4*)(qb + (size_t)u * DIMH + c4 * 4);
            QTt[c4 * 4 + 0][u] = v.x;
            QTt[c4 * 4 + 1][u] = v.y;
            QTt[c4 * 4 + 2][u] = v.z;
            QTt[c4 * 4 + 3][u] = v.w;
        }
        __syncthreads();

        float acc[4][8];
#pragma unroll
        for (int i = 0; i < 4; ++i)
#pragma unroll
            for (int j = 0; j < 8; ++j) acc[i][j] = 0.f;

#pragma unroll 4
        for (int d = 0; d < DIMH; ++d) {
            const float4 qv = *(const float4*)&QTt[d][u0];   // broadcast in group
            const float4 e0 = *(const float4*)&EBt[d][m];
            const float4 e1 = *(const float4*)&EBt[d][m + 4];
            const float4 e2 = *(const float4*)&EBt[d][m + 8];
            const float qa[4] = {qv.x, qv.y, qv.z, qv.w};
            const float ev[12] = {e0.x, e0.y, e0.z, e0.w,
                                  e1.x, e1.y, e1.z, e1.w,
                                  e2.x, e2.y, e2.z, e2.w};
#pragma unroll
            for (int i = 0; i < 4; ++i)
#pragma unroll
                for (int j = 0; j < 8; ++j)
                    acc[i][j] += qa[i] * ev[7 + i - j];   // band row (u-v+127)-m
        }

        // ---- write out[b][h][t0+u0+i][r0+v0 .. +7]
        float* ob = out + (((size_t)b * HEADS + h) * TOKENS + t0 + u0) * (size_t)TOKENS
                  + r0 + v0;
#pragma unroll
        for (int i = 0; i < 4; ++i) {
            float4 w0 = {acc[i][0], acc[i][1], acc[i][2], acc[i][3]};
            float4 w1 = {acc[i][4], acc[i][5], acc[i][6], acc[i][7]};
            float* p = ob + (size_t)i * TOKENS;
            *(float4*)p = w0;
            *((float4*)p + 1) = w1;
        }
    }
}

extern "C" void kernel_launch(void* const* d_in, const int* in_sizes, int n_in,
                              void* d_out, int out_size, void* d_ws, size_t ws_size,
                              hipStream_t stream) {
    const float* q       = (const float*)d_in[0];
    const float* emb     = (const float*)d_in[1];
    const int*   indices = (const int*)d_in[2];
    float* out = (float*)d_out;

    dim3 grid(256);
    dim3 block(NTHREADS);
    relpos_kernel<<<grid, block, 0, stream>>>(q, emb, indices, out);
}

// Round 3
// 105.061 us; speedup vs baseline: 1.2571x; 1.2571x over previous
//
#include <hip/hip_runtime.h>

// out[b,h,t,r] = sum_d q[b,h,t,d] * emb[h, idx[r,t], d],  idx[r,t]=(t-r) mod 1023.
// Write-bound problem (out=67MB, q=8.4MB, emb=2.1MB). Banded bf16 MFMA GEMM:
// per 64x64 (t,r) tile compute P[u][i] = Q . E_band^T (band i in [0,128)),
// epilogue gathers out[u][v] = P[u][u-v+63]. A/B fragments load straight from
// global (no Q/E LDS); the ONLY LDS buffer is Ps, double-fenced per iteration.

#define TOKENS 512
#define DIMH 64
#define NREL 1023
#define IDXN 1490
#define PSTR 132

typedef short bf16x8 __attribute__((ext_vector_type(8)));
typedef float f32x4 __attribute__((ext_vector_type(4)));

__device__ __forceinline__ short f2bf(float x) {  // RNE fp32->bf16
    unsigned u = __float_as_uint(x);
    return (short)((u + 0x7FFFu + ((u >> 16) & 1u)) >> 16);
}
__device__ __forceinline__ bf16x8 cvt8(float4 a, float4 b) {
    bf16x8 r;
    r[0] = f2bf(a.x); r[1] = f2bf(a.y); r[2] = f2bf(a.z); r[3] = f2bf(a.w);
    r[4] = f2bf(b.x); r[5] = f2bf(b.y); r[6] = f2bf(b.z); r[7] = f2bf(b.w);
    return r;
}

__global__ __launch_bounds__(256, 4)
void relpos_mfma2(const float* __restrict__ q,
                  const float* __restrict__ emb,
                  const int* __restrict__ indices,
                  float* __restrict__ out)
{
    __shared__ float Ps[64 * PSTR];   // 33792 B — the only LDS object

    const int tid = threadIdx.x;
    const int blk = blockIdx.x;       // 1024 = rh(2) x tt(8) x bh(64)
    const int rh = blk & 1;
    const int tt = (blk >> 1) & 7;
    const int bh = blk >> 4;
    const int h  = bh & 7;
    const int t0 = tt * 64;

    const int lane = tid & 63;
    const int wave = tid >> 6;
    const int quad = lane >> 4;
    const int l15  = lane & 15;

    // ---- A fragments: once per block, global -> regs (A[m=l15][k=quad*8+j])
    bf16x8 af[4][2];
    {
        const float* qb = q + ((size_t)bh * TOKENS + t0 + l15) * DIMH + quad * 8;
#pragma unroll
        for (int mi = 0; mi < 4; ++mi) {
            const float* p0 = qb + (size_t)mi * 16 * DIMH;
            float4 a0 = *(const float4*)p0;
            float4 a1 = *(const float4*)(p0 + 4);
            float4 b0 = *(const float4*)(p0 + 32);
            float4 b1 = *(const float4*)(p0 + 36);
            af[mi][0] = cvt8(a0, a1);
            af[mi][1] = cvt8(b0, b1);
        }
    }

    const float* embh = emb + (size_t)h * NREL * DIMH;
    const int v4 = (tid & 15) * 4;
    const int u0 = tid >> 4;

    for (int rt = 0; rt < 4; ++rt) {
        const int r0 = rh * 256 + rt * 64;
        // anchor (honest indices read): j_a = idx[r0+63, t0] = (t0-r0-63) mod 1023
        const int j_a = indices[(size_t)(r0 + 63) * IDXN + t0];

        // ---- B fragments: band cols nt = 2*wave + nn, row j=(j_a + nt*16+l15)%1023
        bf16x8 bf[2][2];
#pragma unroll
        for (int nn = 0; nn < 2; ++nn) {
            int j = j_a + (2 * wave + nn) * 16 + l15;
            if (j >= NREL) j -= NREL;
            const float* ep = embh + (size_t)j * DIMH + quad * 8;
            float4 a0 = *(const float4*)ep;
            float4 a1 = *(const float4*)(ep + 4);
            float4 b0 = *(const float4*)(ep + 32);
            float4 b1 = *(const float4*)(ep + 36);
            bf[nn][0] = cvt8(a0, a1);
            bf[nn][1] = cvt8(b0, b1);
        }

        __syncthreads();   // fence: prev epilogue Ps reads complete before writes

#pragma unroll
        for (int nn = 0; nn < 2; ++nn) {
            const int nb = (2 * wave + nn) * 16 + l15;   // band col
#pragma unroll
            for (int mi = 0; mi < 4; ++mi) {
                f32x4 acc = {0.f, 0.f, 0.f, 0.f};
                acc = __builtin_amdgcn_mfma_f32_16x16x32_bf16(af[mi][0], bf[nn][0], acc, 0, 0, 0);
                acc = __builtin_amdgcn_mfma_f32_16x16x32_bf16(af[mi][1], bf[nn][1], acc, 0, 0, 0);
                // C/D: row = quad*4+rg (m), col = l15 (n)
                float* pw = Ps + (size_t)(mi * 16 + quad * 4) * PSTR + nb;
#pragma unroll
                for (int rg = 0; rg < 4; ++rg) pw[rg * PSTR] = acc[rg];
            }
        }

        __syncthreads();   // fence: Ps writes complete before reads

        // ---- epilogue: out[t0+u][r0+v] = Ps[u][u-v+63]
        float* op = out + ((size_t)bh * TOKENS + t0 + u0) * (size_t)TOKENS + r0 + v4;
#pragma unroll
        for (int p = 0; p < 4; ++p) {
            const int u = u0 + p * 16;
            const int base = u - v4 + 63;          // in [3,126]
            const float* pr = Ps + (size_t)u * PSTR;
            float4 o;
            o.x = pr[base];
            o.y = pr[base - 1];
            o.z = pr[base - 2];
            o.w = pr[base - 3];
            *(float4*)(op + (size_t)p * 16 * TOKENS) = o;
        }
    }
}

extern "C" void kernel_launch(void* const* d_in, const int* in_sizes, int n_in,
                              void* d_out, int out_size, void* d_ws, size_t ws_size,
                              hipStream_t stream) {
    const float* q       = (const float*)d_in[0];
    const float* emb     = (const float*)d_in[1];
    const int*   indices = (const int*)d_in[2];
    float* out = (float*)d_out;

    relpos_mfma2<<<dim3(1024), dim3(256), 0, stream>>>(q, emb, indices, out);
}